// Round 3
// baseline (518.128 us; speedup 1.0000x reference)
//
#include <hip/hip_runtime.h>

#define SLEN 2048
#define BATCH 32
#define HDIM 512
#define KDIM 1024   // 2H

typedef _Float16 f16x8 __attribute__((ext_vector_type(8)));
typedef _Float16 f16x4 __attribute__((ext_vector_type(4)));
typedef float f32x4 __attribute__((ext_vector_type(4)));

__device__ __forceinline__ void gload16(const void* g, void* l) {
  __builtin_amdgcn_global_load_lds(
      (const __attribute__((address_space(1))) unsigned int*)g,
      (__attribute__((address_space(3))) unsigned int*)l, 16, 0, 0);
}

__device__ __forceinline__ float fast_tanh(float x) {
  float e = __expf(2.0f * x);
  return 1.0f - 2.0f * __builtin_amdgcn_rcpf(e + 1.0f);
}

// ---- prep: [0,512) W2->f16 | [512,4608) s1 | [4608,4640) zero score |
//      [4640,6688) eo fp32 -> f16 (streaming, 384 MB) ----
__global__ __launch_bounds__(256) void prep_k(const float* __restrict__ attn_w,
                                              const float* __restrict__ attn_b,
                                              const float* __restrict__ hidden,
                                              const float* __restrict__ eo,
                                              _Float16* __restrict__ Bt,
                                              float* __restrict__ s1,
                                              float* __restrict__ score,
                                              _Float16* __restrict__ eo16) {
  if (blockIdx.x < 512) {
    int t = blockIdx.x * 256 + threadIdx.x;
    int h = t >> 8;
    int c = t & 255;
    float4 x = *(const float4*)(attn_w + (size_t)h * 2048 + 1024 + c * 4);
    f16x4 y = {(_Float16)x.x, (_Float16)x.y, (_Float16)x.z, (_Float16)x.w};
    *(f16x4*)(Bt + (size_t)h * 1024 + c * 4) = y;
  } else if (blockIdx.x < 4608) {
    int o = (blockIdx.x - 512) * 4 + (threadIdx.x >> 6);  // one wave per output
    int b = o >> 9, h = o & 511;
    int lane = threadIdx.x & 63;
    const float4* hp = (const float4*)(hidden + (size_t)b * 1024);
    const float4* wp = (const float4*)(attn_w + (size_t)h * 2048);
    float acc = 0.f;
#pragma unroll
    for (int c = 0; c < 4; ++c) {
      float4 a = hp[c * 64 + lane];
      float4 wv = wp[c * 64 + lane];
      acc += a.x * wv.x + a.y * wv.y + a.z * wv.z + a.w * wv.w;
    }
#pragma unroll
    for (int off = 1; off < 64; off <<= 1) acc += __shfl_xor(acc, off);
    if (lane == 0) s1[o] = acc + attn_b[h];
  } else if (blockIdx.x < 4640) {
    int idx = (blockIdx.x - 4608) * 256 + threadIdx.x;
    float4 z = {0.f, 0.f, 0.f, 0.f};
    ((float4*)score)[idx] = z;
    ((float4*)score)[idx + 8192] = z;
  } else {
    // eo [65536][1024] fp32 -> eo16 f16. 8,388,608 8-elem chunks,
    // 524288 threads x 16 iters, fully coalesced.
    int g = (blockIdx.x - 4640) * 256 + threadIdx.x;
    const float4* src = (const float4*)eo;
#pragma unroll
    for (int it = 0; it < 16; ++it) {
      size_t c = (size_t)it * 524288 + g;
      float4 a = src[c * 2];
      float4 b2 = src[c * 2 + 1];
      f16x8 o = {(_Float16)a.x,  (_Float16)a.y,  (_Float16)a.z,  (_Float16)a.w,
                 (_Float16)b2.x, (_Float16)b2.y, (_Float16)b2.z, (_Float16)b2.w};
      *(f16x8*)(eo16 + c * 8) = o;
    }
  }
}

// ---- Main fused GEMM: BM=128, BN=128, BK=32, all-f16 LDS ----
// 4 waves, each owns a 64x64 output quadrant. 3 LDS buffers (A+B 16 KB each,
// 48 KB total -> 3 blocks/CU), DMA prefetch depth 2, counted vmcnt(8).
// LDS swizzle: phys 16B-chunk of row r = logical c ^ ((r>>1)&3); DMA source
// pre-swizzled: lane l -> logical chunk (l&3) ^ ((l>>3)&3).
__global__ __launch_bounds__(256, 3) void gemm_k(const _Float16* __restrict__ eo16,
                                                 const _Float16* __restrict__ Bt,
                                                 const float* __restrict__ s1,
                                                 const float* __restrict__ v,
                                                 float* __restrict__ score) {
  constexpr int BK = 32;
  constexpr int NKT = KDIM / BK;                      // 32
  __shared__ __align__(16) char smem[49152];          // [3x8KB A | 3x8KB B]

  int bid = blockIdx.x;
  // XCD swizzle: the 4 n-tiles of one m-tile land on one XCD (share A in L2)
  int x = bid & 7;
  int q = bid >> 3;
  int nt = q & 3;
  int mt = (q >> 2) * 8 + x;           // 0..511

  int tid = threadIdx.x;
  int lane = tid & 63;
  int w = tid >> 6;
  int wm = (w >> 1) * 64;              // wave m-offset
  int wn = (w & 1) * 64;               // wave n-offset

  // Staging: per wave 2 A-instrs (rows 32w..+32 of 128) + 2 B-instrs.
  const _Float16* ga[2];
  const _Float16* gb[2];
  int swz = ((lane & 3) ^ ((lane >> 3) & 3)) << 3;
#pragma unroll
  for (int i = 0; i < 2; ++i) {
    ga[i] = eo16 + (size_t)(mt * 128 + 32 * w + 16 * i + (lane >> 2)) * KDIM + swz;
    gb[i] = Bt + (size_t)(nt * 128 + 32 * w + 16 * i + (lane >> 2)) * KDIM + swz;
  }

  f32x4 acc[4][4];
#pragma unroll
  for (int i = 0; i < 4; ++i)
#pragma unroll
    for (int j = 0; j < 4; ++j) acc[i][j] = (f32x4){0.f, 0.f, 0.f, 0.f};

  int mrow = lane & 15;
  int quad = lane >> 4;
  int rc = (quad ^ ((mrow >> 1) & 3)) << 3;   // phys chunk (f16 elems) for reads

#define STAGE(buf)                                                    \
  {                                                                   \
    gload16(ga[0], smem + (buf)*8192 + (w * 2 + 0) * 1024);           \
    gload16(ga[1], smem + (buf)*8192 + (w * 2 + 1) * 1024);           \
    ga[0] += BK; ga[1] += BK;                                         \
    gload16(gb[0], smem + 24576 + (buf)*8192 + (w * 2 + 0) * 1024);   \
    gload16(gb[1], smem + 24576 + (buf)*8192 + (w * 2 + 1) * 1024);   \
    gb[0] += BK; gb[1] += BK;                                         \
  }

  // ---- prologue: stage kt=0 -> buf0, kt=1 -> buf1 (8 loads in flight) ----
  STAGE(0);
  STAGE(1);

  int cur = 0, nx2 = 2;
  for (int kt = 0; kt < NKT; ++kt) {
    if (kt + 2 < NKT) {
      STAGE(nx2);                                   // depth-2 prefetch
      asm volatile("s_waitcnt vmcnt(8)" ::: "memory");  // batch kt done
    } else if (kt + 1 < NKT) {
      asm volatile("s_waitcnt vmcnt(4)" ::: "memory");
    } else {
      asm volatile("s_waitcnt vmcnt(0)" ::: "memory");
    }
    __builtin_amdgcn_s_barrier();                   // buf[cur] fully staged

    const _Float16* Ab = (const _Float16*)(smem + cur * 8192);
    const _Float16* Bb = (const _Float16*)(smem + 24576 + cur * 8192);
    f16x8 af[4], bf[4];
#pragma unroll
    for (int i = 0; i < 4; ++i)
      af[i] = *(const f16x8*)&Ab[(wm + 16 * i + mrow) * BK + rc];
#pragma unroll
    for (int j = 0; j < 4; ++j)
      bf[j] = *(const f16x8*)&Bb[(wn + 16 * j + mrow) * BK + rc];

    asm volatile("s_waitcnt lgkmcnt(0)" ::: "memory");
    __builtin_amdgcn_sched_barrier(0);   // rule 18: pin ds_reads above barrier
    __builtin_amdgcn_s_barrier();        // release buf[cur] for later DMA

    __builtin_amdgcn_s_setprio(1);
#pragma unroll
    for (int i = 0; i < 4; ++i)
#pragma unroll
      for (int j = 0; j < 4; ++j)
        acc[i][j] = __builtin_amdgcn_mfma_f32_16x16x32_f16(af[i], bf[j], acc[i][j], 0, 0, 0);
    __builtin_amdgcn_s_setprio(0);

    cur = (cur == 2) ? 0 : cur + 1;
    nx2 = (nx2 == 2) ? 0 : nx2 + 1;
  }
#undef STAGE

  // ---- Epilogue: energy = tanh(acc + s1[b][h]); score += energy * v[h] ----
  __syncthreads();
  float* s1s = (float*)smem;                 // [32][132] (16.9 KB, stride-132)
  float* vsm = (float*)(smem + 48640);       // [128]
  for (int t = tid; t < 1024; t += 256) {
    int bb = t >> 5, cc = t & 31;
    ((float4*)s1s)[bb * 33 + cc] = *(const float4*)(s1 + (size_t)bb * 512 + nt * 128 + cc * 4);
  }
  if (tid < 32) ((float4*)vsm)[tid] = *(const float4*)(v + nt * 128 + tid * 4);
  __syncthreads();

  int lcol = mrow;
  float vv[4];
#pragma unroll
  for (int j = 0; j < 4; ++j) vv[j] = vsm[wn + 16 * j + lcol];

#pragma unroll
  for (int i = 0; i < 4; ++i) {
#pragma unroll
    for (int r = 0; r < 4; ++r) {
      int mloc = wm + 16 * i + 4 * quad + r;
      int bb = mloc & 31;   // mt*128 ≡ 0 (mod 32)
      float sum = 0.f;
#pragma unroll
      for (int j = 0; j < 4; ++j) {
        float e = acc[i][j][r] + s1s[bb * 132 + wn + 16 * j + lcol];
        sum += fast_tanh(e) * vv[j];
      }
      sum += __shfl_xor(sum, 1);
      sum += __shfl_xor(sum, 2);
      sum += __shfl_xor(sum, 4);
      sum += __shfl_xor(sum, 8);
      if (lcol == 0) {
        int mg = mt * 128 + mloc;        // global row m = s*32 + b
        atomicAdd(&score[(mg & 31) * SLEN + (mg >> 5)], sum);
      }
    }
  }
}

// ---- Masked softmax over s for each b; score stored b-major [32][2048] ----
__global__ __launch_bounds__(256) void softmax_k(const float* __restrict__ score,
                                                 const int* __restrict__ mask,
                                                 float* __restrict__ out) {
  int b = blockIdx.x;
  int tid = threadIdx.x;
  int lane = tid & 63, w = tid >> 6;
  __shared__ float red[8];
  float vals[8];
  float mx = -3.4e38f;
#pragma unroll
  for (int i = 0; i < 8; ++i) {
    int s = i * 256 + tid;
    float xv = score[b * SLEN + s];
    if (mask[b * SLEN + s] == 0) xv = -1e10f;
    vals[i] = xv;
    mx = fmaxf(mx, xv);
  }
#pragma unroll
  for (int off = 1; off < 64; off <<= 1) mx = fmaxf(mx, __shfl_xor(mx, off));
  if (lane == 0) red[w] = mx;
  __syncthreads();
  mx = fmaxf(fmaxf(red[0], red[1]), fmaxf(red[2], red[3]));
  float sum = 0.f;
#pragma unroll
  for (int i = 0; i < 8; ++i) {
    vals[i] = __expf(vals[i] - mx);
    sum += vals[i];
  }
#pragma unroll
  for (int off = 1; off < 64; off <<= 1) sum += __shfl_xor(sum, off);
  if (lane == 0) red[4 + w] = sum;
  __syncthreads();
  sum = red[4] + red[5] + red[6] + red[7];
  float inv = 1.0f / sum;
#pragma unroll
  for (int i = 0; i < 8; ++i) out[b * SLEN + i * 256 + tid] = vals[i] * inv;
}

extern "C" void kernel_launch(void* const* d_in, const int* in_sizes, int n_in,
                              void* d_out, int out_size, void* d_ws, size_t ws_size,
                              hipStream_t stream) {
  const float* hidden = (const float*)d_in[0];
  const float* eo     = (const float*)d_in[1];
  const int*   mask   = (const int*)d_in[2];
  const float* attn_w = (const float*)d_in[3];
  const float* attn_b = (const float*)d_in[4];
  const float* v      = (const float*)d_in[5];
  float* out = (float*)d_out;

  char* wsb = (char*)d_ws;
  _Float16* Bt = (_Float16*)wsb;                              // 1 MB
  float* s1    = (float*)(wsb + (1 << 20));                   // 64 KB
  float* score = (float*)(wsb + (1 << 20) + (1 << 16));       // 256 KB
  _Float16* eo16 = (_Float16*)(wsb + (2 << 20));              // 128 MB

  prep_k<<<6688, 256, 0, stream>>>(attn_w, attn_b, hidden, eo, Bt, s1, score, eo16);
  gemm_k<<<2048, 256, 0, stream>>>(eo16, Bt, s1, v, score);
  softmax_k<<<BATCH, 256, 0, stream>>>(score, mask, out);
}

// Round 4
// 484.019 us; speedup vs baseline: 1.0705x; 1.0705x over previous
//
#include <hip/hip_runtime.h>

#define SLEN 2048
#define BATCH 32
#define HDIM 512
#define KDIM 1024   // 2H

typedef _Float16 f16x8 __attribute__((ext_vector_type(8)));
typedef _Float16 f16x4 __attribute__((ext_vector_type(4)));
typedef float f32x4 __attribute__((ext_vector_type(4)));

__device__ __forceinline__ float fast_tanh(float x) {
  float e = __expf(2.0f * x);
  return 1.0f - 2.0f * __builtin_amdgcn_rcpf(e + 1.0f);
}

// ---- prep: [0,512) W2->f16 | [512,4608) s1 | [4608,4640) zero score ----
__global__ __launch_bounds__(256) void prep_k(const float* __restrict__ attn_w,
                                              const float* __restrict__ attn_b,
                                              const float* __restrict__ hidden,
                                              _Float16* __restrict__ Bt,
                                              float* __restrict__ s1,
                                              float* __restrict__ score) {
  if (blockIdx.x < 512) {
    int t = blockIdx.x * 256 + threadIdx.x;
    int h = t >> 8;
    int c = t & 255;
    float4 x = *(const float4*)(attn_w + (size_t)h * 2048 + 1024 + c * 4);
    f16x4 y = {(_Float16)x.x, (_Float16)x.y, (_Float16)x.z, (_Float16)x.w};
    *(f16x4*)(Bt + (size_t)h * 1024 + c * 4) = y;
  } else if (blockIdx.x < 4608) {
    int o = (blockIdx.x - 512) * 4 + (threadIdx.x >> 6);  // one wave per output
    int b = o >> 9, h = o & 511;
    int lane = threadIdx.x & 63;
    const float4* hp = (const float4*)(hidden + (size_t)b * 1024);
    const float4* wp = (const float4*)(attn_w + (size_t)h * 2048);
    float acc = 0.f;
#pragma unroll
    for (int c = 0; c < 4; ++c) {
      float4 a = hp[c * 64 + lane];
      float4 wv = wp[c * 64 + lane];
      acc += a.x * wv.x + a.y * wv.y + a.z * wv.z + a.w * wv.w;
    }
#pragma unroll
    for (int off = 1; off < 64; off <<= 1) acc += __shfl_xor(acc, off);
    if (lane == 0) s1[o] = acc + attn_b[h];
  } else {
    int idx = (blockIdx.x - 4608) * 256 + threadIdx.x;
    float4 z = {0.f, 0.f, 0.f, 0.f};
    ((float4*)score)[idx] = z;
    ((float4*)score)[idx + 8192] = z;
  }
}

// ---- Main fused GEMM: BM=128, BN=128, BK=32, REGISTER-STAGED (no DMA) ----
// A loaded fp32 from global -> cvt f16 in-reg -> ds_write; B f16 direct.
// LDS rows padded to 40 f16 (80 B): reads AND writes bank-optimal (8 dw/bank).
// Pipeline: loads for tile t issued at iter t-2 (counted vmcnt(6) keeps the
// younger 6 in flight across raw s_barrier); ds_write of t+1 overlaps MFMA(t).
// 1 barrier/iter. 2 LDS buffers x 20 KB = 40 KB -> 3 blocks/CU (VGPR-capped).
__global__ __launch_bounds__(256, 3) void gemm_k(const float* __restrict__ eo,
                                                 const _Float16* __restrict__ Bt,
                                                 const float* __restrict__ s1,
                                                 const float* __restrict__ v,
                                                 float* __restrict__ score) {
  constexpr int NKT = KDIM / 32;                 // 32 K-tiles
  __shared__ __align__(16) char smem[40960];     // buf0 @0, buf1 @20480; B at +10240

  int bid = blockIdx.x;
  // XCD swizzle: 4 n-tiles of one m-tile land on one XCD (share A in its L2)
  int x = bid & 7;
  int q = bid >> 3;
  int nt = q & 3;
  int mt = (q >> 2) * 8 + x;           // 0..511

  int tid = threadIdx.x;
  int lane = tid & 63;
  int w = tid >> 6;
  int wm = (w >> 1) * 64;              // wave m-offset
  int wn = (w & 1) * 64;               // wave n-offset
  int mrow = lane & 15;
  int quad = lane >> 4;

  // Per-lane staging addresses: lane handles row 32w+(lane>>1), 16 k-elems
  // starting at (lane&1)*16.
  const float* aBase = eo + (size_t)(mt * 128 + 32 * w + (lane >> 1)) * KDIM + (lane & 1) * 16;
  const _Float16* bBase = Bt + (size_t)(nt * 128 + 32 * w + (lane >> 1)) * KDIM + (lane & 1) * 16;
  int wrOff = (32 * w + (lane >> 1)) * 80 + (lane & 1) * 32;  // byte off in tile

  char* sm = (char*)smem;

  f32x4 acc[4][4];
#pragma unroll
  for (int i = 0; i < 4; ++i)
#pragma unroll
    for (int j = 0; j < 4; ++j) acc[i][j] = (f32x4){0.f, 0.f, 0.f, 0.f};

  float4 A0a, A0b, A0c, A0d, B0a, B0b;   // reg set 0
  float4 A1a, A1b, A1c, A1d, B1a, B1b;   // reg set 1

#define LOADREG(Aa, Ab, Ac, Ad, Ba, Bb, T)                        \
  {                                                               \
    int kc = ((T) < NKT ? (T) : NKT - 1) * 32;                    \
    Aa = *(const float4*)(aBase + kc);                            \
    Ab = *(const float4*)(aBase + kc + 4);                        \
    Ac = *(const float4*)(aBase + kc + 8);                        \
    Ad = *(const float4*)(aBase + kc + 12);                       \
    Ba = *(const float4*)(bBase + kc);                            \
    Bb = *(const float4*)(bBase + kc + 8);                        \
  }

#define WRITEBUF(BASE, Aa, Ab, Ac, Ad, Ba, Bb)                                    \
  {                                                                               \
    f16x8 p0 = {(_Float16)Aa.x, (_Float16)Aa.y, (_Float16)Aa.z, (_Float16)Aa.w,  \
                (_Float16)Ab.x, (_Float16)Ab.y, (_Float16)Ab.z, (_Float16)Ab.w}; \
    f16x8 p1 = {(_Float16)Ac.x, (_Float16)Ac.y, (_Float16)Ac.z, (_Float16)Ac.w,  \
                (_Float16)Ad.x, (_Float16)Ad.y, (_Float16)Ad.z, (_Float16)Ad.w}; \
    *(f16x8*)(sm + (BASE) + wrOff) = p0;                                          \
    *(f16x8*)(sm + (BASE) + wrOff + 16) = p1;                                     \
    *(float4*)(sm + (BASE) + 10240 + wrOff) = Ba;                                 \
    *(float4*)(sm + (BASE) + 10240 + wrOff + 16) = Bb;                            \
  }

#define KSTEP(CURB, OTHB, Aa, Ab, Ac, Ad, Ba, Bb, TNEXT)                          \
  {                                                                               \
    f16x8 af0 = *(const f16x8*)(sm + (CURB) + (wm + mrow) * 80 + quad * 16);      \
    f16x8 af1 = *(const f16x8*)(sm + (CURB) + (wm + 16 + mrow) * 80 + quad * 16); \
    f16x8 af2 = *(const f16x8*)(sm + (CURB) + (wm + 32 + mrow) * 80 + quad * 16); \
    f16x8 af3 = *(const f16x8*)(sm + (CURB) + (wm + 48 + mrow) * 80 + quad * 16); \
    f16x8 bf0 = *(const f16x8*)(sm + (CURB) + 10240 + (wn + mrow) * 80 + quad * 16);      \
    f16x8 bf1 = *(const f16x8*)(sm + (CURB) + 10240 + (wn + 16 + mrow) * 80 + quad * 16); \
    f16x8 bf2 = *(const f16x8*)(sm + (CURB) + 10240 + (wn + 32 + mrow) * 80 + quad * 16); \
    f16x8 bf3 = *(const f16x8*)(sm + (CURB) + 10240 + (wn + 48 + mrow) * 80 + quad * 16); \
    __builtin_amdgcn_s_setprio(1);                                                \
    acc[0][0] = __builtin_amdgcn_mfma_f32_16x16x32_f16(af0, bf0, acc[0][0], 0, 0, 0); \
    acc[0][1] = __builtin_amdgcn_mfma_f32_16x16x32_f16(af0, bf1, acc[0][1], 0, 0, 0); \
    acc[0][2] = __builtin_amdgcn_mfma_f32_16x16x32_f16(af0, bf2, acc[0][2], 0, 0, 0); \
    acc[0][3] = __builtin_amdgcn_mfma_f32_16x16x32_f16(af0, bf3, acc[0][3], 0, 0, 0); \
    acc[1][0] = __builtin_amdgcn_mfma_f32_16x16x32_f16(af1, bf0, acc[1][0], 0, 0, 0); \
    acc[1][1] = __builtin_amdgcn_mfma_f32_16x16x32_f16(af1, bf1, acc[1][1], 0, 0, 0); \
    acc[1][2] = __builtin_amdgcn_mfma_f32_16x16x32_f16(af1, bf2, acc[1][2], 0, 0, 0); \
    acc[1][3] = __builtin_amdgcn_mfma_f32_16x16x32_f16(af1, bf3, acc[1][3], 0, 0, 0); \
    acc[2][0] = __builtin_amdgcn_mfma_f32_16x16x32_f16(af2, bf0, acc[2][0], 0, 0, 0); \
    acc[2][1] = __builtin_amdgcn_mfma_f32_16x16x32_f16(af2, bf1, acc[2][1], 0, 0, 0); \
    acc[2][2] = __builtin_amdgcn_mfma_f32_16x16x32_f16(af2, bf2, acc[2][2], 0, 0, 0); \
    acc[2][3] = __builtin_amdgcn_mfma_f32_16x16x32_f16(af2, bf3, acc[2][3], 0, 0, 0); \
    acc[3][0] = __builtin_amdgcn_mfma_f32_16x16x32_f16(af3, bf0, acc[3][0], 0, 0, 0); \
    acc[3][1] = __builtin_amdgcn_mfma_f32_16x16x32_f16(af3, bf1, acc[3][1], 0, 0, 0); \
    acc[3][2] = __builtin_amdgcn_mfma_f32_16x16x32_f16(af3, bf2, acc[3][2], 0, 0, 0); \
    acc[3][3] = __builtin_amdgcn_mfma_f32_16x16x32_f16(af3, bf3, acc[3][3], 0, 0, 0); \
    __builtin_amdgcn_s_setprio(0);                                                \
    asm volatile("s_waitcnt vmcnt(6)" ::: "memory");                              \
    WRITEBUF(OTHB, Aa, Ab, Ac, Ad, Ba, Bb);                                       \
    LOADREG(Aa, Ab, Ac, Ad, Ba, Bb, TNEXT);                                       \
    asm volatile("s_waitcnt lgkmcnt(0)" ::: "memory");                            \
    __builtin_amdgcn_sched_barrier(0);                                            \
    __builtin_amdgcn_s_barrier();                                                 \
  }

  // ---- prologue: t=0 -> buf0 via regs; t=1 (set0) & t=2 (set1) in flight ----
  LOADREG(A0a, A0b, A0c, A0d, B0a, B0b, 0);
  asm volatile("s_waitcnt vmcnt(0)" ::: "memory");
  WRITEBUF(0, A0a, A0b, A0c, A0d, B0a, B0b);
  LOADREG(A0a, A0b, A0c, A0d, B0a, B0b, 1);
  LOADREG(A1a, A1b, A1c, A1d, B1a, B1b, 2);
  asm volatile("s_waitcnt lgkmcnt(0)" ::: "memory");
  __builtin_amdgcn_sched_barrier(0);
  __builtin_amdgcn_s_barrier();

#pragma unroll 1
  for (int it = 0; it < NKT / 2; ++it) {
    KSTEP(0, 20480, A0a, A0b, A0c, A0d, B0a, B0b, 2 * it + 3);       // kt even
    KSTEP(20480, 0, A1a, A1b, A1c, A1d, B1a, B1b, 2 * it + 4);       // kt odd
  }
#undef KSTEP
#undef WRITEBUF
#undef LOADREG

  // ---- Epilogue: energy = tanh(acc + s1[b][h]); score += energy * v[h] ----
  __syncthreads();
  float* s1s = (float*)smem;                 // [32][132] fp32 (stride-132)
  float* vsm = (float*)(smem + 16896);       // [128]
  for (int t = tid; t < 1024; t += 256) {
    int bb = t >> 5, cc = t & 31;
    ((float4*)s1s)[bb * 33 + cc] = *(const float4*)(s1 + (size_t)bb * 512 + nt * 128 + cc * 4);
  }
  if (tid < 32) ((float4*)vsm)[tid] = *(const float4*)(v + nt * 128 + tid * 4);
  __syncthreads();

  int lcol = mrow;
  float vv[4];
#pragma unroll
  for (int j = 0; j < 4; ++j) vv[j] = vsm[wn + 16 * j + lcol];

#pragma unroll
  for (int i = 0; i < 4; ++i) {
#pragma unroll
    for (int r = 0; r < 4; ++r) {
      int mloc = wm + 16 * i + 4 * quad + r;
      int bb = mloc & 31;   // mt*128 ≡ 0 (mod 32)
      float sum = 0.f;
#pragma unroll
      for (int j = 0; j < 4; ++j) {
        float e = acc[i][j][r] + s1s[bb * 132 + wn + 16 * j + lcol];
        sum += fast_tanh(e) * vv[j];
      }
      sum += __shfl_xor(sum, 1);
      sum += __shfl_xor(sum, 2);
      sum += __shfl_xor(sum, 4);
      sum += __shfl_xor(sum, 8);
      if (lcol == 0) {
        int mg = mt * 128 + mloc;        // global row m = s*32 + b
        atomicAdd(&score[(mg & 31) * SLEN + (mg >> 5)], sum);
      }
    }
  }
}

// ---- Masked softmax over s for each b; score stored b-major [32][2048] ----
__global__ __launch_bounds__(256) void softmax_k(const float* __restrict__ score,
                                                 const int* __restrict__ mask,
                                                 float* __restrict__ out) {
  int b = blockIdx.x;
  int tid = threadIdx.x;
  int lane = tid & 63, w = tid >> 6;
  __shared__ float red[8];
  float vals[8];
  float mx = -3.4e38f;
#pragma unroll
  for (int i = 0; i < 8; ++i) {
    int s = i * 256 + tid;
    float xv = score[b * SLEN + s];
    if (mask[b * SLEN + s] == 0) xv = -1e10f;
    vals[i] = xv;
    mx = fmaxf(mx, xv);
  }
#pragma unroll
  for (int off = 1; off < 64; off <<= 1) mx = fmaxf(mx, __shfl_xor(mx, off));
  if (lane == 0) red[w] = mx;
  __syncthreads();
  mx = fmaxf(fmaxf(red[0], red[1]), fmaxf(red[2], red[3]));
  float sum = 0.f;
#pragma unroll
  for (int i = 0; i < 8; ++i) {
    vals[i] = __expf(vals[i] - mx);
    sum += vals[i];
  }
#pragma unroll
  for (int off = 1; off < 64; off <<= 1) sum += __shfl_xor(sum, off);
  if (lane == 0) red[4 + w] = sum;
  __syncthreads();
  sum = red[4] + red[5] + red[6] + red[7];
  float inv = 1.0f / sum;
#pragma unroll
  for (int i = 0; i < 8; ++i) out[b * SLEN + i * 256 + tid] = vals[i] * inv;
}

extern "C" void kernel_launch(void* const* d_in, const int* in_sizes, int n_in,
                              void* d_out, int out_size, void* d_ws, size_t ws_size,
                              hipStream_t stream) {
  const float* hidden = (const float*)d_in[0];
  const float* eo     = (const float*)d_in[1];
  const int*   mask   = (const int*)d_in[2];
  const float* attn_w = (const float*)d_in[3];
  const float* attn_b = (const float*)d_in[4];
  const float* v      = (const float*)d_in[5];
  float* out = (float*)d_out;

  char* wsb = (char*)d_ws;
  _Float16* Bt = (_Float16*)wsb;                              // 1 MB
  float* s1    = (float*)(wsb + (1 << 20));                   // 64 KB
  float* score = (float*)(wsb + (1 << 20) + (1 << 16));       // 256 KB

  prep_k<<<4640, 256, 0, stream>>>(attn_w, attn_b, hidden, Bt, s1, score);
  gemm_k<<<2048, 256, 0, stream>>>(eo, Bt, s1, v, score);
  softmax_k<<<BATCH, 256, 0, stream>>>(score, mask, out);
}